// Round 4
// baseline (298.708 us; speedup 1.0000x reference)
//
#include <hip/hip_runtime.h>
#include <math.h>

// SegmentedTensorSquareSelfInteraction on MI355X (gfx950) — fused, streaming-B, 2 blocks/CU.
// N=32768, MUL0=256, MUL1=128, G=64, INV_DIM=448, used gates=576, out=(N,640) fp32
//
// Two dispatches:
//  1. wcast : weights -> bf16 in MFMA *fragment order*:
//             BF[tile][kc][lane][8] = B[k = kc*32+(lane>>4)*8+e][col = tile*16+(lane&15)]
//             Coalesced-read version: thread reads 8 consecutive cols of one row (32B),
//             scatters 8 bf16 stores into the fragment layout.
//  2. fused : per block of BM=32 nodes, whole chain, zero HBM intermediates, barrier-free
//             GEMM k-loops (B streamed from L2-resident fragment-ordered weights):
//     A: s_all -> LDS sa[32][472]
//     B: h = silu(sa @ W1 * s1) -> LDS hb      (stream W1F, MT=1 NT=7)
//     C: gates = hb @ W2 * s1 (single NT=9 pass); u = sa*g0 -> hb; g1 -> LDS g1[32][128]
//        wmat[(r*3+i)][m] = v*g1 -> overlays sa ([96][136])
//     D: o0 = u @ Wl0 * s1 -> LayerNorm -> out[:, :256]
//     E: o1 = wmat @ Wl1 * s2 -> RMS over (3,128) -> out[:, 256:640]  (MT=3 NT=2)
// LDS: sa 30,208 + hb 30,208 + g1 8,192 + red 1,664 = 70,272 B -> 2 blocks/CU, 16 waves/CU.
// ws usage: 1,179,648 bytes (fragment-ordered bf16 weights only).

typedef float floatx4 __attribute__((ext_vector_type(4)));
typedef __bf16 bf16x8 __attribute__((ext_vector_type(8)));

__device__ __forceinline__ unsigned short f2bf(float f) {
    union { float f; unsigned u; } v; v.f = f;
    unsigned r = v.u + 0x7FFFu + ((v.u >> 16) & 1u);  // round-to-nearest-even
    return (unsigned short)(r >> 16);
}
__device__ __forceinline__ float bf2f(unsigned short u) {
    union { unsigned u; float f; } v; v.u = ((unsigned)u) << 16; return v.f;
}

// ---------------------------------------------------------------- weight cast
// Thread -> (k, tile t, col-half c8): reads W[k][t*16+c8*8 .. +7] (32B coalesced),
// writes 8 bf16 into fragment order: dst = ((t*NKC + k>>5)*64 + ((k>>3)&3)*16 + c8*8 + d)*8 + (k&7).
__global__ __launch_bounds__(256) void wcast_kernel(
    const float* __restrict__ W1, const float* __restrict__ W2,
    const float* __restrict__ Wl0, const float* __restrict__ Wl1,
    unsigned short* __restrict__ W1F, unsigned short* __restrict__ W2F,
    unsigned short* __restrict__ Wl0F, unsigned short* __restrict__ Wl1F)
{
    int idx = blockIdx.x * 256 + threadIdx.x;
    const float* src; unsigned short* dst;
    int T, NKC, ld, k, rem;
    if (idx < 25088) {                       // W1F: 448 rows x (28 tiles x 2)
        k = idx / 56; rem = idx % 56; src = W1; dst = W1F; T = 28; NKC = 14; ld = 448;
    } else if (idx < 57344) {                // W2F: 448 rows x (36 tiles x 2), first 576 cols
        int r = idx - 25088;
        k = r / 72; rem = r % 72; src = W2; dst = W2F; T = 36; NKC = 14; ld = 832;
    } else if (idx < 71680) {                // Wl0F: 448 rows x (16 tiles x 2)
        int r = idx - 57344;
        k = r / 32; rem = r % 32; src = Wl0; dst = Wl0F; T = 16; NKC = 14; ld = 256;
    } else if (idx < 73728) {                // Wl1F: 128 rows x (8 tiles x 2)
        int r = idx - 71680;
        k = r / 16; rem = r % 16; src = Wl1; dst = Wl1F; T = 8; NKC = 4; ld = 128;
    } else return;
    int t = rem >> 1, c8 = rem & 1;
    const float* s = src + (size_t)k * ld + t * 16 + c8 * 8;
    float4 f0 = *(const float4*)s;
    float4 f1 = *(const float4*)(s + 4);
    int kc = k >> 5, q = (k >> 3) & 3, e = k & 7;
    unsigned short* base = dst + ((size_t)(t * NKC + kc) * 64 + q * 16 + c8 * 8) * 8 + e;
    float v[8] = {f0.x, f0.y, f0.z, f0.w, f1.x, f1.y, f1.z, f1.w};
    #pragma unroll
    for (int d = 0; d < 8; ++d) base[d * 8] = f2bf(v[d]);
}

// ---------------------------------------------------------------- streaming GEMM core
// acc[MT][NT] += A_lds[rows] @ B (fragment-ordered global, L2-resident). No barriers,
// no LDS staging: per kc, MT ds_read_b128 (A) + NT coalesced 16B global loads (B) + MFMAs.
template<int MT, int NT, int NKC>
__device__ __forceinline__ void gemm_stream(
    const unsigned short* __restrict__ BF, const int tileBase,
    const unsigned short* __restrict__ Albs, const int ldsA, const int rowBase,
    const int lane, const int l15, const int quad, const int wn,
    floatx4 (&acc)[MT][NT])
{
    const unsigned short* bp[NT];
    #pragma unroll
    for (int j = 0; j < NT; ++j)
        bp[j] = BF + ((size_t)(tileBase + wn + 4 * j) * NKC * 64 + lane) * 8;
    #pragma unroll
    for (int kc = 0; kc < NKC; ++kc) {
        bf16x8 af[MT];
        #pragma unroll
        for (int mt = 0; mt < MT; ++mt)
            af[mt] = *(const bf16x8*)&Albs[(rowBase + mt * 16 + l15) * ldsA + kc * 32 + quad * 8];
        #pragma unroll
        for (int j = 0; j < NT; ++j) {
            bf16x8 bfv = *(const bf16x8*)(bp[j] + kc * 512);
            #pragma unroll
            for (int mt = 0; mt < MT; ++mt)
                acc[mt][j] = __builtin_amdgcn_mfma_f32_16x16x32_bf16(af[mt], bfv, acc[mt][j], 0, 0, 0);
        }
    }
}

// ---------------------------------------------------------------- fused megakernel
__global__ __launch_bounds__(512, 4) void fused_kernel(
    const float* __restrict__ x,
    const unsigned short* __restrict__ W1F,
    const unsigned short* __restrict__ W2F,
    const unsigned short* __restrict__ Wl0F,
    const unsigned short* __restrict__ Wl1F,
    float* __restrict__ out)
{
    __shared__ unsigned short sa[32][472];   // s_all; later wmat overlay [96][136]
    __shared__ unsigned short hb[32][472];   // h, then u
    __shared__ unsigned short g1[32][128];   // g1o gates
    __shared__ float red[416];               // LN partials [32][8] | rowSq [96][4] + nodeRms @384

    const int tid  = threadIdx.x;
    const int lane = tid & 63;
    const int l15  = lane & 15;
    const int quad = lane >> 4;
    const int w    = tid >> 6;
    const int wm   = w >> 2;        // 0..1 : rows wm*16 (stages B/C/D), wm*48 (stage E)
    const int wn   = w & 3;         // 0..3 : N-tile = wn + 4*j
    const int n0   = blockIdx.x * 32;

    const float s1 = 0.047245559f;  // 1/sqrt(448)
    const float s2 = 0.088388348f;  // 1/sqrt(128)

    // ---- stage A: s_all -> sa ----
    {
        const int r = tid >> 4, sub = tid & 15;    // 16 threads per row
        const float* xr = x + (size_t)(n0 + r) * 640;
        #pragma unroll
        for (int i = 0; i < 4; ++i) {              // s part: 64 float4 per row
            int c4 = i * 16 + sub;
            float4 f = *(const float4*)(xr + c4 * 4);
            uint2 p;
            p.x = (unsigned)f2bf(f.x) | ((unsigned)f2bf(f.y) << 16);
            p.y = (unsigned)f2bf(f.z) | ((unsigned)f2bf(f.w) << 16);
            *(uint2*)&sa[r][c4 * 4] = p;
        }
        const float* xv = xr + 256;
        #pragma unroll
        for (int i = 0; i < 4; ++i) {              // t0 part: 64 groups per row
            int g = i * 16 + sub;
            const float2* vg = (const float2*)(xv + 6 * g);
            float2 p0 = vg[0], p1 = vg[1], p2 = vg[2];
            float ax = p0.x, ay = p0.y, az = p1.x;
            float bx = p1.y, by = p2.x, bz = p2.y;
            float aa = ax*ax + ay*ay + az*az;
            float ab = ax*bx + ay*by + az*bz;
            float bb = bx*bx + by*by + bz*bz;
            const float ISQ3 = 0.57735026918962576f;
            const float SQ2  = 1.41421356237309505f;
            sa[r][256 + 3*g]     = f2bf(aa * ISQ3);
            sa[r][256 + 3*g + 1] = f2bf(SQ2 * ab * ISQ3);
            sa[r][256 + 3*g + 2] = f2bf(bb * ISQ3);
        }
    }
    __syncthreads();                               // sa ready

    // ---- stage B: h = silu(sa @ W1 * s1) -> hb ----
    {
        floatx4 acc[1][7] = {};
        gemm_stream<1,7,14>(W1F, 0, &sa[0][0], 472, wm*16, lane, l15, quad, wn, acc);
        #pragma unroll
        for (int j = 0; j < 7; ++j) {
            const int col = (wn + 4*j) * 16 + l15;
            #pragma unroll
            for (int r = 0; r < 4; ++r) {
                float v = acc[0][j][r] * s1;
                v = v / (1.f + __expf(-v));
                hb[wm*16 + quad*4 + r][col] = f2bf(v);
            }
        }
    }
    __syncthreads();                               // hb(h) ready

    // ---- stage C: gates = hb @ W2 * s1 (single NT=9 pass); u -> hb; g1 -> g1[][] ----
    {
        floatx4 acc[1][9] = {};
        gemm_stream<1,9,14>(W2F, 0, &hb[0][0], 472, wm*16, lane, l15, quad, wn, acc);
        __syncthreads();                           // all hb(h) reads complete
        #pragma unroll
        for (int j = 0; j < 9; ++j) {
            const int colb = (wn + 4*j) * 16;      // wave-uniform, 0..560
            if (colb < 448) {                      // g0 -> u = sa * g0
                const int col = colb + l15;
                #pragma unroll
                for (int r = 0; r < 4; ++r) {
                    const int row = wm*16 + quad*4 + r;
                    hb[row][col] = f2bf(bf2f(sa[row][col]) * (acc[0][j][r] * s1));
                }
            } else {                               // g1o
                const int m = colb - 448 + l15;
                #pragma unroll
                for (int r = 0; r < 4; ++r) {
                    const int row = wm*16 + quad*4 + r;
                    g1[row][m] = f2bf(acc[0][j][r] * s1);
                }
            }
        }
    }
    __syncthreads();                               // u/g1 ready; sa dead

    // ---- wmat build: wmat[(r*3+i)][m] = v[r][m][i] * g1[r][m] -> overlays sa ----
    {
        unsigned short* wmp = &sa[0][0];           // [96][136]
        #pragma unroll
        for (int e0 = 0; e0 < 3072; e0 += 512) {   // 32 rows * 96 float4
            int e4 = e0 + tid;
            int rl = e4 / 96;
            int c4 = (e4 - rl * 96) * 4;           // float index in v-row (0..383)
            float4 xv = *(const float4*)(x + (size_t)(n0 + rl) * 640 + 256 + c4);
            float vv[4] = {xv.x, xv.y, xv.z, xv.w};
            #pragma unroll
            for (int d = 0; d < 4; ++d) {
                int rem = c4 + d;
                int m = rem / 3;
                int i = rem - 3 * m;
                wmp[(rl * 3 + i) * 136 + m] = f2bf(vv[d] * bf2f(g1[rl][m]));
            }
        }
    }
    __syncthreads();                               // wmat ready

    // ---- stage D: o0 = u @ Wl0 * s1 -> LayerNorm -> out[:, :256] ----
    {
        floatx4 acc[1][4] = {};
        gemm_stream<1,4,14>(Wl0F, 0, &hb[0][0], 472, wm*16, lane, l15, quad, wn, acc);
        #pragma unroll
        for (int r = 0; r < 4; ++r) {
            float sv = 0.f, sq = 0.f;
            #pragma unroll
            for (int j = 0; j < 4; ++j) {
                float v = acc[0][j][r] * s1;
                sv += v; sq += v * v;
            }
            #pragma unroll
            for (int off = 1; off <= 8; off <<= 1) {
                sv += __shfl_xor(sv, off);
                sq += __shfl_xor(sq, off);
            }
            if (l15 == 0) {
                const int row = wm*16 + quad*4 + r;
                red[row * 8 + wn * 2]     = sv;
                red[row * 8 + wn * 2 + 1] = sq;
            }
        }
        __syncthreads();                           // LN partials ready
        #pragma unroll
        for (int r = 0; r < 4; ++r) {
            const int row = wm*16 + quad*4 + r;
            float ts = red[row*8+0] + red[row*8+2] + red[row*8+4] + red[row*8+6];
            float tq = red[row*8+1] + red[row*8+3] + red[row*8+5] + red[row*8+7];
            float mu  = ts * (1.f/256.f);
            float var = tq * (1.f/256.f) - mu * mu;
            float rln = rsqrtf(var + 1e-6f);
            float* orow = out + (size_t)(n0 + row) * 640;
            #pragma unroll
            for (int j = 0; j < 4; ++j)
                orow[(wn + 4*j)*16 + l15] = (acc[0][j][r] * s1 - mu) * rln;
        }
    }
    __syncthreads();                               // stage-D red reads done before E writes red

    // ---- stage E: o1 = wmat @ Wl1 * s2 -> RMS over (3,128) -> out[:, 256:640] ----
    {
        floatx4 acc[3][2] = {};
        gemm_stream<3,2,4>(Wl1F, 0, &sa[0][0] /*wmat*/, 136, wm*48, lane, l15, quad, wn, acc);
        #pragma unroll
        for (int mt = 0; mt < 3; ++mt)
            #pragma unroll
            for (int r = 0; r < 4; ++r) {
                float q = 0.f;
                #pragma unroll
                for (int j = 0; j < 2; ++j) {
                    float v = acc[mt][j][r] * s2;
                    q += v * v;
                }
                #pragma unroll
                for (int off = 1; off <= 8; off <<= 1) q += __shfl_xor(q, off);
                if (l15 == 0) {
                    const int row = wm*48 + mt*16 + quad*4 + r;
                    red[row * 4 + wn] = q;
                }
            }
        __syncthreads();
        if (tid < 32) {                            // per-node rrms
            float s = 0.f;
            #pragma unroll
            for (int rr = 0; rr < 3; ++rr)
                #pragma unroll
                for (int w2 = 0; w2 < 4; ++w2)
                    s += red[(tid*3 + rr) * 4 + w2];
            red[384 + tid] = rsqrtf(s * (1.f/384.f) + 1e-6f);
        }
        __syncthreads();
        #pragma unroll
        for (int mt = 0; mt < 3; ++mt)
            #pragma unroll
            for (int r = 0; r < 4; ++r) {
                const int row = wm*48 + mt*16 + quad*4 + r;
                const int nl  = row / 3;
                const int i   = row - 3 * nl;
                const float rms = red[384 + nl];
                float* op = out + (size_t)(n0 + nl) * 640 + 256 + i;
                #pragma unroll
                for (int j = 0; j < 2; ++j)
                    op[3 * ((wn + 4*j)*16 + l15)] = acc[mt][j][r] * s2 * rms;
            }
    }
}

// ---------------------------------------------------------------- launch
extern "C" void kernel_launch(void* const* d_in, const int* in_sizes, int n_in,
                              void* d_out, int out_size, void* d_ws, size_t ws_size,
                              hipStream_t stream) {
    const float* x   = (const float*)d_in[0];
    const float* W1  = (const float*)d_in[1];
    const float* W2  = (const float*)d_in[2];
    const float* Wl0 = (const float*)d_in[3];
    const float* Wl1 = (const float*)d_in[4];
    float* out = (float*)d_out;
    char* ws = (char*)d_ws;

    unsigned short* W1F  = (unsigned short*)(ws + 0);         // 401,408 B
    unsigned short* W2F  = (unsigned short*)(ws + 401408);    // 516,096 B
    unsigned short* Wl0F = (unsigned short*)(ws + 917504);    // 229,376 B
    unsigned short* Wl1F = (unsigned short*)(ws + 1146880);   //  32,768 B
    // peak ws: 1,179,648 bytes

    wcast_kernel<<<dim3(288), dim3(256), 0, stream>>>(W1, W2, Wl0, Wl1, W1F, W2F, Wl0F, Wl1F);
    fused_kernel<<<dim3(1024), dim3(512), 0, stream>>>(x, W1F, W2F, Wl0F, Wl1F, out);
}

// Round 5
// 248.271 us; speedup vs baseline: 1.2032x; 1.2032x over previous
//
#include <hip/hip_runtime.h>
#include <math.h>

// SegmentedTensorSquareSelfInteraction on MI355X (gfx950) — fused, streaming-B, MT=4.
// N=32768, MUL0=256, MUL1=128, G=64, INV_DIM=448, used gates=576, out=(N,640) fp32
//
// R5: wave layout 1x8 over N (each wave owns ALL 64 rows -> MT=4, max B-fragment reuse),
//     N padded to multiples of 128 (W1F 512, W2F 640; zero-filled pads, outputs skipped).
//     Per-block B-traffic 2.3MB -> 1.26MB (L2-stream was the measured bottleneck).
//
// Two dispatches:
//  1. wcast : weights -> bf16 fragment order BF[tile][kc][lane][8], zero-padded tiles.
//  2. fused : per block of 64 nodes, whole chain, zero HBM intermediates, barrier-free
//             GEMM k-loops (B streamed from L2-resident fragment-ordered weights):
//     A: s_all -> LDS sa[64][472]
//     B: h = silu(sa @ W1 * s1) -> LDS hb      (MT=4, NT=4, pad 512)
//     C: gates = hb @ W2 * s1 (MT=4, NT=5, pad 640); u = sa*g0 -> hb; g1 -> LDS
//        wmat[(r*3+i)][m] = v*g1 -> overlays sa ([192][136])
//     D: o0 = u @ Wl0 * s1 (MT=4, NT=2) -> LayerNorm -> out[:, :256]
//     E: o1 = wmat @ Wl1 * s2 (MT=12, NT=1) -> RMS over (3,128) -> out[:, 256:640]
// LDS: sa 60,416 + hb 60,416 + g1 16,384 + red 6,400 = 143,616 B -> 1 block/CU, 8 waves.
// ws usage: 1,294,336 bytes (fragment-ordered bf16 weights only).

typedef float floatx4 __attribute__((ext_vector_type(4)));
typedef __bf16 bf16x8 __attribute__((ext_vector_type(8)));

__device__ __forceinline__ unsigned short f2bf(float f) {
    __bf16 h = (__bf16)f;                    // RNE; compiler can pair into v_cvt_pk_bf16_f32
    return __builtin_bit_cast(unsigned short, h);
}
__device__ __forceinline__ float bf2f(unsigned short u) {
    union { unsigned u; float f; } v; v.u = ((unsigned)u) << 16; return v.f;
}

// ---------------------------------------------------------------- weight cast
// Thread -> (k, tile t, col-half c8): reads W[k][t*16+c8*8 .. +7] (32B coalesced),
// scatters 8 bf16 into fragment order; pad tiles (col >= colTrue) write zeros.
__global__ __launch_bounds__(256) void wcast_kernel(
    const float* __restrict__ W1, const float* __restrict__ W2,
    const float* __restrict__ Wl0, const float* __restrict__ Wl1,
    unsigned short* __restrict__ W1F, unsigned short* __restrict__ W2F,
    unsigned short* __restrict__ Wl0F, unsigned short* __restrict__ Wl1F)
{
    int idx = blockIdx.x * 256 + threadIdx.x;
    const float* src; unsigned short* dst;
    int NKC, ld, colTrue, k, rem;
    if (idx < 28672) {                        // W1F: 448 rows x (32 tiles x 2)
        k = idx / 64; rem = idx % 64; src = W1; dst = W1F; NKC = 14; ld = 448; colTrue = 448;
    } else if (idx < 64512) {                 // W2F: 448 rows x (40 tiles x 2)
        int r = idx - 28672;
        k = r / 80; rem = r % 80; src = W2; dst = W2F; NKC = 14; ld = 832; colTrue = 576;
    } else if (idx < 78848) {                 // Wl0F: 448 rows x (16 tiles x 2)
        int r = idx - 64512;
        k = r / 32; rem = r % 32; src = Wl0; dst = Wl0F; NKC = 14; ld = 256; colTrue = 256;
    } else if (idx < 80896) {                 // Wl1F: 128 rows x (8 tiles x 2)
        int r = idx - 78848;
        k = r / 16; rem = r % 16; src = Wl1; dst = Wl1F; NKC = 4; ld = 128; colTrue = 128;
    } else return;
    int t = rem >> 1, c8 = rem & 1;
    int col0 = t * 16 + c8 * 8;
    float v[8] = {0.f, 0.f, 0.f, 0.f, 0.f, 0.f, 0.f, 0.f};
    if (col0 < colTrue) {
        const float* s = src + (size_t)k * ld + col0;
        float4 f0 = *(const float4*)s;
        float4 f1 = *(const float4*)(s + 4);
        v[0]=f0.x; v[1]=f0.y; v[2]=f0.z; v[3]=f0.w;
        v[4]=f1.x; v[5]=f1.y; v[6]=f1.z; v[7]=f1.w;
    }
    int kc = k >> 5, q = (k >> 3) & 3, e = k & 7;
    unsigned short* base = dst + ((size_t)(t * NKC + kc) * 64 + q * 16 + c8 * 8) * 8 + e;
    #pragma unroll
    for (int d = 0; d < 8; ++d) base[d * 8] = f2bf(v[d]);
}

// ---------------------------------------------------------------- streaming GEMM core
// acc[MT][NT] += A_lds[rows] @ B (fragment-ordered global, L2-resident). No barriers,
// no LDS staging. Wave wn owns N-tiles {wn + 8*j}. Each B-fragment feeds MT MFMAs.
template<int MT, int NT, int NKC>
__device__ __forceinline__ void gemm_stream(
    const unsigned short* __restrict__ BF,
    const unsigned short* __restrict__ Albs, const int ldsA, const int rowBase,
    const int lane, const int l15, const int quad, const int wn,
    floatx4 (&acc)[MT][NT])
{
    const unsigned short* bp[NT];
    #pragma unroll
    for (int j = 0; j < NT; ++j)
        bp[j] = BF + ((size_t)(wn + 8 * j) * NKC * 64 + lane) * 8;
    #pragma unroll
    for (int kc = 0; kc < NKC; ++kc) {
        bf16x8 af[MT];
        #pragma unroll
        for (int mt = 0; mt < MT; ++mt)
            af[mt] = *(const bf16x8*)&Albs[(rowBase + mt * 16 + l15) * ldsA + kc * 32 + quad * 8];
        #pragma unroll
        for (int j = 0; j < NT; ++j) {
            bf16x8 bfv = *(const bf16x8*)(bp[j] + kc * 512);
            #pragma unroll
            for (int mt = 0; mt < MT; ++mt)
                acc[mt][j] = __builtin_amdgcn_mfma_f32_16x16x32_bf16(af[mt], bfv, acc[mt][j], 0, 0, 0);
        }
    }
}

// ---------------------------------------------------------------- fused megakernel
__global__ __launch_bounds__(512, 2) void fused_kernel(
    const float* __restrict__ x,
    const unsigned short* __restrict__ W1F,
    const unsigned short* __restrict__ W2F,
    const unsigned short* __restrict__ Wl0F,
    const unsigned short* __restrict__ Wl1F,
    float* __restrict__ out)
{
    __shared__ unsigned short sa[64][472];   // s_all; later wmat overlay [192][136]
    __shared__ unsigned short hb[64][472];   // h, then u
    __shared__ unsigned short g1[64][128];   // g1o gates
    __shared__ float red[1600];              // LN sv[64][8] | sq @512 ; E q[192][8] ; rms @1536

    const int tid  = threadIdx.x;
    const int lane = tid & 63;
    const int l15  = lane & 15;
    const int quad = lane >> 4;
    const int wn   = tid >> 6;      // 0..7 : N-tile = wn + 8*j (all waves own all rows)
    const int n0   = blockIdx.x * 64;

    const float s1 = 0.047245559f;  // 1/sqrt(448)
    const float s2 = 0.088388348f;  // 1/sqrt(128)

    // ---- stage A: s_all -> sa ----
    {
        const int r = tid >> 3, sub = tid & 7;     // 8 threads per row
        const float* xr = x + (size_t)(n0 + r) * 640;
        #pragma unroll
        for (int i = 0; i < 8; ++i) {              // s part: 64 float4 per row
            int c4 = i * 8 + sub;
            float4 f = *(const float4*)(xr + c4 * 4);
            unsigned short* o = &sa[r][c4 * 4];
            o[0] = f2bf(f.x); o[1] = f2bf(f.y); o[2] = f2bf(f.z); o[3] = f2bf(f.w);
        }
        const float* xv = xr + 256;
        #pragma unroll
        for (int i = 0; i < 8; ++i) {              // t0 part: 64 groups per row
            int g = i * 8 + sub;
            const float2* vg = (const float2*)(xv + 6 * g);
            float2 p0 = vg[0], p1 = vg[1], p2 = vg[2];
            float ax = p0.x, ay = p0.y, az = p1.x;
            float bx = p1.y, by = p2.x, bz = p2.y;
            float aa = ax*ax + ay*ay + az*az;
            float ab = ax*bx + ay*by + az*bz;
            float bb = bx*bx + by*by + bz*bz;
            const float ISQ3 = 0.57735026918962576f;
            const float SQ2  = 1.41421356237309505f;
            sa[r][256 + 3*g]     = f2bf(aa * ISQ3);
            sa[r][256 + 3*g + 1] = f2bf(SQ2 * ab * ISQ3);
            sa[r][256 + 3*g + 2] = f2bf(bb * ISQ3);
        }
    }
    __syncthreads();                               // sa ready

    // ---- stage B: h = silu(sa @ W1 * s1) -> hb  (pad 512, skip tiles >= 28) ----
    {
        floatx4 acc[4][4] = {};
        gemm_stream<4,4,14>(W1F, &sa[0][0], 472, 0, lane, l15, quad, wn, acc);
        #pragma unroll
        for (int j = 0; j < 4; ++j) {
            const int colb = (wn + 8*j) * 16;      // wave-uniform
            if (colb < 448) {
                const int col = colb + l15;
                #pragma unroll
                for (int mt = 0; mt < 4; ++mt)
                    #pragma unroll
                    for (int r = 0; r < 4; ++r) {
                        float v = acc[mt][j][r] * s1;
                        v = v / (1.f + __expf(-v));
                        hb[mt*16 + quad*4 + r][col] = f2bf(v);
                    }
            }
        }
    }
    __syncthreads();                               // hb(h) ready

    // ---- stage C: gates = hb @ W2 * s1 (pad 640); u -> hb; g1 -> g1[][] ----
    {
        floatx4 acc[4][5] = {};
        gemm_stream<4,5,14>(W2F, &hb[0][0], 472, 0, lane, l15, quad, wn, acc);
        __syncthreads();                           // all hb(h) reads complete
        #pragma unroll
        for (int j = 0; j < 5; ++j) {
            const int colb = (wn + 8*j) * 16;      // wave-uniform, 0..624
            if (colb < 448) {                      // g0 -> u = sa * g0
                const int col = colb + l15;
                #pragma unroll
                for (int mt = 0; mt < 4; ++mt)
                    #pragma unroll
                    for (int r = 0; r < 4; ++r) {
                        const int row = mt*16 + quad*4 + r;
                        hb[row][col] = f2bf(bf2f(sa[row][col]) * (acc[mt][j][r] * s1));
                    }
            } else if (colb < 576) {               // g1o
                const int m = colb - 448 + l15;
                #pragma unroll
                for (int mt = 0; mt < 4; ++mt)
                    #pragma unroll
                    for (int r = 0; r < 4; ++r) {
                        const int row = mt*16 + quad*4 + r;
                        g1[row][m] = f2bf(acc[mt][j][r] * s1);
                    }
            }
        }
    }
    __syncthreads();                               // u/g1 ready; sa dead

    // ---- wmat build: wmat[(r*3+i)][m] = v[r][m][i] * g1[r][m] -> overlays sa ----
    {
        unsigned short* wmp = &sa[0][0];           // [192][136]
        #pragma unroll
        for (int e0 = 0; e0 < 6144; e0 += 512) {   // 64 rows * 96 float4
            int e4 = e0 + tid;
            int rl = e4 / 96;
            int c4 = (e4 - rl * 96) * 4;           // float index in v-row (0..383)
            float4 xv = *(const float4*)(x + (size_t)(n0 + rl) * 640 + 256 + c4);
            float vv[4] = {xv.x, xv.y, xv.z, xv.w};
            #pragma unroll
            for (int d = 0; d < 4; ++d) {
                int rem = c4 + d;
                int m = rem / 3;
                int i = rem - 3 * m;
                wmp[(rl * 3 + i) * 136 + m] = f2bf(vv[d] * bf2f(g1[rl][m]));
            }
        }
    }
    __syncthreads();                               // wmat ready

    // ---- stage D: o0 = u @ Wl0 * s1 -> LayerNorm -> out[:, :256] ----
    {
        floatx4 acc[4][2] = {};
        gemm_stream<4,2,14>(Wl0F, &hb[0][0], 472, 0, lane, l15, quad, wn, acc);
        #pragma unroll
        for (int mt = 0; mt < 4; ++mt)
            #pragma unroll
            for (int r = 0; r < 4; ++r) {
                float sv = 0.f, sq = 0.f;
                #pragma unroll
                for (int j = 0; j < 2; ++j) {
                    float v = acc[mt][j][r] * s1;
                    sv += v; sq += v * v;
                }
                #pragma unroll
                for (int off = 1; off <= 8; off <<= 1) {
                    sv += __shfl_xor(sv, off);
                    sq += __shfl_xor(sq, off);
                }
                if (l15 == 0) {
                    const int row = mt*16 + quad*4 + r;
                    red[row * 8 + wn]       = sv;
                    red[512 + row * 8 + wn] = sq;
                }
            }
        __syncthreads();                           // LN partials ready
        #pragma unroll
        for (int mt = 0; mt < 4; ++mt)
            #pragma unroll
            for (int r = 0; r < 4; ++r) {
                const int row = mt*16 + quad*4 + r;
                float ts = 0.f, tq = 0.f;
                #pragma unroll
                for (int w2 = 0; w2 < 8; ++w2) {
                    ts += red[row*8 + w2];
                    tq += red[512 + row*8 + w2];
                }
                float mu  = ts * (1.f/256.f);
                float var = tq * (1.f/256.f) - mu * mu;
                float rln = rsqrtf(var + 1e-6f);
                float* orow = out + (size_t)(n0 + row) * 640;
                #pragma unroll
                for (int j = 0; j < 2; ++j)
                    orow[(wn + 8*j)*16 + l15] = (acc[mt][j][r] * s1 - mu) * rln;
            }
    }
    __syncthreads();                               // stage-D red reads done before E writes red

    // ---- stage E: o1 = wmat @ Wl1 * s2 -> RMS over (3,128) -> out[:, 256:640] ----
    {
        floatx4 acc[12][1] = {};
        gemm_stream<12,1,4>(Wl1F, &sa[0][0] /*wmat*/, 136, 0, lane, l15, quad, wn, acc);
        #pragma unroll
        for (int mt = 0; mt < 12; ++mt)
            #pragma unroll
            for (int r = 0; r < 4; ++r) {
                float v = acc[mt][0][r] * s2;
                float q = v * v;
                #pragma unroll
                for (int off = 1; off <= 8; off <<= 1) q += __shfl_xor(q, off);
                if (l15 == 0) {
                    const int row = mt*16 + quad*4 + r;
                    red[row * 8 + wn] = q;
                }
            }
        __syncthreads();
        if (tid < 64) {                            // per-node rrms
            float s = 0.f;
            #pragma unroll
            for (int rr = 0; rr < 3; ++rr)
                #pragma unroll
                for (int w2 = 0; w2 < 8; ++w2)
                    s += red[(tid*3 + rr) * 8 + w2];
            red[1536 + tid] = rsqrtf(s * (1.f/384.f) + 1e-6f);
        }
        __syncthreads();
        #pragma unroll
        for (int mt = 0; mt < 12; ++mt)
            #pragma unroll
            for (int r = 0; r < 4; ++r) {
                const int row = mt*16 + quad*4 + r;
                const int nl  = row / 3;
                const int i   = row - 3 * nl;
                const float rms = red[1536 + nl];
                float* op = out + (size_t)(n0 + nl) * 640 + 256 + i;
                op[3 * (wn*16 + l15)] = acc[mt][0][r] * s2 * rms;
            }
    }
}

// ---------------------------------------------------------------- launch
extern "C" void kernel_launch(void* const* d_in, const int* in_sizes, int n_in,
                              void* d_out, int out_size, void* d_ws, size_t ws_size,
                              hipStream_t stream) {
    const float* x   = (const float*)d_in[0];
    const float* W1  = (const float*)d_in[1];
    const float* W2  = (const float*)d_in[2];
    const float* Wl0 = (const float*)d_in[3];
    const float* Wl1 = (const float*)d_in[4];
    float* out = (float*)d_out;
    char* ws = (char*)d_ws;

    unsigned short* W1F  = (unsigned short*)(ws + 0);         // 458,752 B (512x448)
    unsigned short* W2F  = (unsigned short*)(ws + 458752);    // 573,440 B (640x448)
    unsigned short* Wl0F = (unsigned short*)(ws + 1032192);   // 229,376 B (256x448)
    unsigned short* Wl1F = (unsigned short*)(ws + 1261568);   //  32,768 B (128x128)
    // peak ws: 1,294,336 bytes

    wcast_kernel<<<dim3(316), dim3(256), 0, stream>>>(W1, W2, Wl0, Wl1, W1F, W2F, Wl0F, Wl1F);
    fused_kernel<<<dim3(512), dim3(512), 0, stream>>>(x, W1F, W2F, Wl0F, Wl1F, out);
}